// Round 3
// baseline (304.856 us; speedup 1.0000x reference)
//
#include <hip/hip_runtime.h>
#include <math.h>

#define B_  32
#define C_  384
#define HW  1024

typedef float          f32x4 __attribute__((ext_vector_type(4)));
typedef short          s16x8 __attribute__((ext_vector_type(8)));
typedef unsigned short us8v  __attribute__((ext_vector_type(8)));

struct KParams {
  const float* x;
  const float* mw1[3]; const float* mb1[3]; const float* mw2[3]; const float* mb2[3];
  const float* cw[3];  const float* cb[3];
  const float* fw1; const float* fb1; const float* fw2; const float* fb2;
  const float* pw;  const float* pb;
  float* wg;            // [3][B][C]
  float* H_part;        // [B][2][8][36]
  float* cvA;           // [B][2][5][96]  {T, C0, C1, C30, C31} (atomic-accumulated)
  float* ext;           // [B][2][2][10][96] {Ra,Rb, 8 corner pixels} for q0/q7
  unsigned short* pwT;  // [384 d][384 k'] bf16, k' permuted
  float* out;
};

__device__ __forceinline__ float gelu_exact(float v) {
  return 0.5f * v * (1.0f + erff(v * 0.70710678118654752440f));
}
__device__ __forceinline__ unsigned short f2bf(float f) {
  unsigned u = __float_as_uint(f);
  u += 0x7FFFu + ((u >> 16) & 1u);
  return (unsigned short)(u >> 16);
}
__device__ __forceinline__ float bf2f(unsigned short h) {
  return __uint_as_float(((unsigned)h) << 16);
}

// ---------------------------------------------------------------------------
// k_prep: pwT[d][k'] = bf16(pw[gc(k')][d]); k' permutation: [mlp0, mlp1, cv0, cv1]
// ---------------------------------------------------------------------------
__global__ __launch_bounds__(256) void k_prep(KParams P) {
  __shared__ float tile[32][33];
  const int td = blockIdx.x % 12, tc = blockIdx.x / 12;
  const int j = threadIdx.x & 31, i0 = threadIdx.x >> 5;
  const int gcoff = (tc < 3) ? 0 : (tc < 6 ? 96 : (tc < 9 ? -96 : 0));
  for (int i = i0; i < 32; i += 8)
    tile[i][j] = P.pw[(size_t)(tc*32 + i + gcoff)*C_ + td*32 + j];
  __syncthreads();
  for (int i = i0; i < 32; i += 8)
    P.pwT[(size_t)(td*32 + i)*C_ + tc*32 + j] = f2bf(tile[j][i]);
}

// ---------------------------------------------------------------------------
// conv window for k_proj recompute (verified round-2 code)
// ---------------------------------------------------------------------------
template<int HALF>
__device__ __forceinline__ void conv_strip(const float* xc, int h0, int row,
                                           float w1t, const float* w3, const float* w5,
                                           float* y0, float* y1, float* y2) {
#pragma unroll
  for (int p = 0; p < 16; ++p) { y0[p] = 0.f; y1[p] = 0.f; y2[p] = 0.f; }
#pragma unroll
  for (int dy = 0; dy < 5; ++dy) {
    const int hr = h0 + row - 2 + dy;
    float win[20];
    if (hr >= 0 && hr < 32) {
#pragma unroll
      for (int u = 0; u < 5; ++u)
        *(float4*)&win[u*4] = *(const float4*)&xc[hr*32 + HALF*12 + u*4];
    } else {
#pragma unroll
      for (int u = 0; u < 20; ++u) win[u] = 0.f;
    }
#pragma unroll
    for (int dx = 0; dx < 5; ++dx) {
      const float w = w5[dy*5 + dx];
#pragma unroll
      for (int p = 0; p < 16; ++p) {
        const int ri = p + dx - 2 + HALF*4;
        if (ri >= 0 && ri < 20) y2[p] += win[ri] * w;
      }
    }
    if (dy >= 1 && dy <= 3) {
#pragma unroll
      for (int dx = 0; dx < 3; ++dx) {
        const float w = w3[(dy-1)*3 + dx];
#pragma unroll
        for (int p = 0; p < 16; ++p) {
          const int ri = p + dx - 1 + HALF*4;
          if (ri >= 0 && ri < 20) y1[p] += win[ri] * w;
        }
      }
      if (dy == 2) {
#pragma unroll
        for (int p = 0; p < 16; ++p) y0[p] = win[p + HALF*4] * w1t;
      }
    }
  }
}

// ---------------------------------------------------------------------------
// k_sum: grid = b(32) x sub(32).  sub<16: MLP-sum block (mi,q).
// sub>=16: conv-stat block (gi,q) -> cvA (atomics) + ext (q0/q7).
// ---------------------------------------------------------------------------
__global__ __launch_bounds__(256, 2) void k_sum(KParams P) {
  __shared__ __align__(16) char sm[49152 + 13824 + 256];
  const int bid = blockIdx.x;
  const int b = bid >> 5, sub = bid & 31;
  const int t = threadIdx.x;

  if (sub < 16) {
    const int mi = sub >> 3, q = sub & 7;
    const int h0 = q * 4;
    float* Xl  = (float*)sm;                     // [96][128]
    float* w1l = (float*)(sm + 49152);           // [s][c][j]
    float* Hl  = (float*)(sm + 49152 + 13824);   // [36]
    for (int i = t; i < 3456; i += 256) {
      int s = i / 1152, r = i - s*1152;
      w1l[i] = P.mw1[s][mi*1152 + r];
    }
    for (int i = t*4; i < 12288; i += 1024) {
      int c = i >> 7, pix = i & 127;
      *(float4*)&Xl[i] = *(const float4*)&P.x[(size_t)(b*C_ + mi*192 + c)*HW + h0*32 + pix];
    }
    __syncthreads();
    const int quad = t & 31, sjg = t >> 6;
    const int cq = (t >> 5) & 1;
    const int sj0 = sjg * 9;
    float h[9][4];
#pragma unroll
    for (int u = 0; u < 9; ++u) { h[u][0]=0.f; h[u][1]=0.f; h[u][2]=0.f; h[u][3]=0.f; }
    int wbase[9];
#pragma unroll
    for (int u = 0; u < 9; ++u) {
      int sj = sj0 + u, s = sj / 12, jj = sj % 12;
      wbase[u] = s*1152 + jj;
    }
    for (int c = cq*48; c < cq*48 + 48; ++c) {
      const float4 xv = *(const float4*)&Xl[c*128 + quad*4];
#pragma unroll
      for (int u = 0; u < 9; ++u) {
        const float w = w1l[wbase[u] + c*12];
        h[u][0] += xv.x*w; h[u][1] += xv.y*w; h[u][2] += xv.z*w; h[u][3] += xv.w*w;
      }
    }
#pragma unroll
    for (int u = 0; u < 9; ++u)
#pragma unroll
      for (int p = 0; p < 4; ++p) h[u][p] += __shfl_xor(h[u][p], 32, 64);
    float hs[9];
#pragma unroll
    for (int u = 0; u < 9; ++u) {
      int sj = sj0 + u, s = sj / 12, jj = sj % 12;
      const float bias = P.mb1[s][mi*12 + jj];
      float sum = 0.f;
#pragma unroll
      for (int p = 0; p < 4; ++p) sum += gelu_exact(h[u][p] + bias);
#pragma unroll
      for (int m = 16; m >= 1; m >>= 1) sum += __shfl_xor(sum, m, 64);
      hs[u] = sum;
    }
    if ((t & 63) == 0) {
#pragma unroll
      for (int u = 0; u < 9; ++u) Hl[sj0 + u] = hs[u];
    }
    __syncthreads();
    if (t < 36) P.H_part[(size_t)((b*2 + mi)*8 + q)*36 + t] = Hl[t];
  } else {
    // ---- conv border-stat block ----
    const int s2 = sub - 16;
    const int gi = s2 >> 3, q = s2 & 7;
    const int h0 = q * 4;
    const int lane = t & 63, wv = t >> 6;
    const int gcbase = (2*gi + 1) * 96;
    for (int i = 0; i < 24; ++i) {
      const int cc = wv*24 + i;
      const float* xc = P.x + (size_t)(b*C_ + gcbase + cc)*HW + h0*32;
      const float2 v = *(const float2*)(xc + 2*lane);   // pix 2*lane, 2*lane+1
      const float t2 = v.x + v.y;
      float T = t2;
      T += __shfl_xor(T, 1, 64);  T += __shfl_xor(T, 2, 64);
      T += __shfl_xor(T, 4, 64);  T += __shfl_xor(T, 8, 64);
      T += __shfl_xor(T, 16, 64); T += __shfl_xor(T, 32, 64);
      float c0  = ((lane & 15) == 0)  ? v.x : 0.f;
      float c1  = ((lane & 15) == 0)  ? v.y : 0.f;
      float c30 = ((lane & 15) == 15) ? v.x : 0.f;
      float c31 = ((lane & 15) == 15) ? v.y : 0.f;
      c0  += __shfl_xor(c0, 16, 64);  c0  += __shfl_xor(c0, 32, 64);
      c1  += __shfl_xor(c1, 16, 64);  c1  += __shfl_xor(c1, 32, 64);
      c30 += __shfl_xor(c30, 16, 64); c30 += __shfl_xor(c30, 32, 64);
      c31 += __shfl_xor(c31, 16, 64); c31 += __shfl_xor(c31, 32, 64);
      if (lane == 0) {
        float* A = &P.cvA[(size_t)(b*2 + gi)*5*96 + cc];
        atomicAdd(A + 0*96, T);   atomicAdd(A + 1*96, c0);
        atomicAdd(A + 2*96, c1);  atomicAdd(A + 3*96, c30);
        atomicAdd(A + 4*96, c31);
      }
      if (q == 0 || q == 7) {
        float r = t2;
        r += __shfl_xor(r, 1, 64); r += __shfl_xor(r, 2, 64);
        r += __shfl_xor(r, 4, 64); r += __shfl_xor(r, 8, 64);
        const int e  = (q == 0) ? 0 : 1;
        const int lo = (q == 0) ? 0 : 32;   // q0: rows 0,1 = lanes 0-31; q7: rows 30,31 = lanes 32-63
        const float Ra  = __shfl(r,   lo,      64), Rb  = __shfl(r,   lo + 16, 64);
        const float p00 = __shfl(v.x, lo,      64), p01 = __shfl(v.y, lo,      64);
        const float p0a = __shfl(v.x, lo + 15, 64), p0b = __shfl(v.y, lo + 15, 64);
        const float p10 = __shfl(v.x, lo + 16, 64), p11 = __shfl(v.y, lo + 16, 64);
        const float p1a = __shfl(v.x, lo + 31, 64), p1b = __shfl(v.y, lo + 31, 64);
        if (lane == 0) {
          float* E = &P.ext[((size_t)(b*2 + gi)*2 + e)*10*96 + cc];
          E[0*96] = Ra;  E[1*96] = Rb;
          E[2*96] = p00; E[3*96] = p01; E[4*96] = p0a; E[5*96] = p0b;
          E[6*96] = p10; E[7*96] = p11; E[8*96] = p1a; E[9*96] = p1b;
        }
      }
    }
  }
}

// ---------------------------------------------------------------------------
// k_gate: finish sums -> a[c] -> fusion MLP -> softmax. grid=B, 256 threads.
// ---------------------------------------------------------------------------
__global__ __launch_bounds__(256) void k_gate(KParams P) {
  const int b = blockIdx.x, t = threadIdx.x;
  __shared__ float am[C_], g1p[2][96], g1v[96], Hs[2][36];
  for (int i = t; i < 72; i += 256) {
    int mi = i / 36, sj = i % 36;
    float s = 0.f;
    for (int q = 0; q < 8; ++q) s += P.H_part[(size_t)((b*2+mi)*8 + q)*36 + sj];
    Hs[mi][sj] = s * (1.0f/1024.0f);
  }
  __syncthreads();
  // MLP-chunk means via layer 2
  for (int i = t; i < 192; i += 256) {
    int mi = i / 96, cc = i % 96;
    float a = 0.f;
    for (int s = 0; s < 3; ++s) {
      float y = P.mb2[s][mi*96 + cc];
      for (int jj = 0; jj < 12; ++jj) y += Hs[mi][s*12+jj] * P.mw2[s][mi*1152 + jj*96 + cc];
      a += y;
    }
    am[mi*192 + cc] = a;
  }
  // conv-chunk means via border stats (inclusion-exclusion)
  for (int i = t; i < 192; i += 256) {
    const int gi = i / 96, cc = i % 96;
    const float* A  = &P.cvA[(size_t)(b*2 + gi)*5*96 + cc];
    const float T   = A[0*96];
    const float C0  = A[1*96], C1  = A[2*96], C30 = A[3*96], C31 = A[4*96];
    const float* E0 = &P.ext[((size_t)(b*2 + gi)*2 + 0)*10*96 + cc];
    const float* E1 = &P.ext[((size_t)(b*2 + gi)*2 + 1)*10*96 + cc];
    const float R0  = E0[0*96], R1  = E0[1*96];
    const float a00 = E0[2*96], a01 = E0[3*96], a0a = E0[4*96], a0b = E0[5*96];
    const float a10 = E0[6*96], a11 = E0[7*96], a1a = E0[8*96], a1b = E0[9*96];
    const float R30 = E1[0*96], R31 = E1[1*96];
    const float b00 = E1[2*96], b01 = E1[3*96], b0a = E1[4*96], b0b = E1[5*96];
    const float b10 = E1[6*96], b11 = E1[7*96], b1a = E1[8*96], b1b = E1[9*96];
    // indexed by shift+2 (shift in [-2,2])
    const float ER[5]   = {R30+R31, R31, 0.f, R0, R0+R1};
    const float EC[5]   = {C30+C31, C31, 0.f, C0, C0+C1};
    const float cr0[5]  = {a0a+a0b, a0b, 0.f, a00, a00+a01};   // row 0, excluded-col sums
    const float cr1[5]  = {a1a+a1b, a1b, 0.f, a10, a10+a11};   // row 1
    const float cr30[5] = {b0a+b0b, b0b, 0.f, b00, b00+b01};   // row 30
    const float cr31[5] = {b1a+b1b, b1b, 0.f, b10, b10+b11};   // row 31
    const int gcl = gi*96 + cc;
    float sum = P.cw[0][gcl] * T;
#pragma unroll
    for (int dy = 0; dy < 3; ++dy)
#pragma unroll
      for (int dx = 0; dx < 3; ++dx) {
        const int s = dy - 1, u = dx - 1;
        float xc_ = 0.f;
        if (s == 1)  xc_ = cr0[u+2];
        if (s == -1) xc_ = cr31[u+2];
        sum += P.cw[1][gcl*9 + dy*3 + dx] * (T - ER[s+2] - EC[u+2] + xc_);
      }
#pragma unroll
    for (int dy = 0; dy < 5; ++dy)
#pragma unroll
      for (int dx = 0; dx < 5; ++dx) {
        const int s = dy - 2, u = dx - 2;
        float xc_ = 0.f;
        if (s == 1)  xc_ = cr0[u+2];
        if (s == 2)  xc_ = cr0[u+2] + cr1[u+2];
        if (s == -1) xc_ = cr31[u+2];
        if (s == -2) xc_ = cr30[u+2] + cr31[u+2];
        sum += P.cw[2][gcl*25 + dy*5 + dx] * (T - ER[s+2] - EC[u+2] + xc_);
      }
    am[(2*gi+1)*96 + cc] = sum * (1.0f/1024.0f)
                         + P.cb[0][gcl] + P.cb[1][gcl] + P.cb[2][gcl];
  }
  __syncthreads();
  if (t < 192) {
    const int jj = t % 96, half = t / 96;
    float acc = 0.f;
    for (int c = half*192; c < half*192 + 192; ++c) acc += am[c] * P.fw1[c*96 + jj];
    g1p[half][jj] = acc;
  }
  __syncthreads();
  if (t < 96) g1v[t] = gelu_exact(g1p[0][t] + g1p[1][t] + P.fb1[t]);
  __syncthreads();
  for (int c = t; c < C_; c += 256) {
    float l0 = P.fb2[c*3+0], l1 = P.fb2[c*3+1], l2 = P.fb2[c*3+2];
    for (int jj = 0; jj < 96; ++jj) {
      const float g = g1v[jj];
      const float* f = P.fw2 + jj*1152 + c*3;
      l0 += g*f[0]; l1 += g*f[1]; l2 += g*f[2];
    }
    const float m = fmaxf(l0, fmaxf(l1, l2));
    const float e0 = expf(l0-m), e1 = expf(l1-m), e2 = expf(l2-m);
    const float inv = 1.0f/(e0+e1+e2);
    P.wg[0*(B_*C_) + b*C_ + c] = e0*inv;
    P.wg[1*(B_*C_) + b*C_ + c] = e1*inv;
    P.wg[2*(B_*C_) + b*C_ + c] = e2*inv;
  }
}

// ---------------------------------------------------------------------------
// k_proj: grid = b(32) x rowquad(8), 1024 threads (16 waves).
// ---------------------------------------------------------------------------
template<int HALF>
__device__ __forceinline__ void conv_phase2(const KParams& P, int b, int h0,
                                            char* combB, const float* wgl, int tt) {
  for (int it = 0; it < 2; ++it) {
    const int task = tt + 512*it;
    if (task < 768) {
      const int row = task & 3, c192 = task >> 2;
      const int gi = c192 / 96, cc = c192 - gi*96;
      const int gcl = gi*96 + cc;
      const int gc = (2*gi + 1)*96 + cc;
      const int kp = 192 + gi*96 + cc;
      const float* xc = P.x + (size_t)(b*C_ + gc)*HW;
      const float w1t = P.cw[0][gcl];
      float w3[9], w5[25];
#pragma unroll
      for (int k2 = 0; k2 < 9; ++k2)  w3[k2] = P.cw[1][gcl*9 + k2];
#pragma unroll
      for (int k2 = 0; k2 < 25; ++k2) w5[k2] = P.cw[2][gcl*25 + k2];
      float y0[16], y1[16], y2[16];
      conv_strip<HALF>(xc, h0, row, w1t, w3, w5, y0, y1, y2);
      const float g0 = wgl[0*C_ + gc], g1 = wgl[1*C_ + gc], g2 = wgl[2*C_ + gc];
      const float cbg = g0*P.cb[0][gcl] + g1*P.cb[1][gcl] + g2*P.cb[2][gcl];
#pragma unroll
      for (int p = 0; p < 16; ++p) {
        const float v = g0*y0[p] + g1*y1[p] + g2*y2[p] + cbg;
        const int pix = row*32 + HALF*16 + p;
        const int off = pix*768 + ((kp*2) ^ ((pix & 15) << 4));
        *(unsigned short*)(combB + off) = f2bf(v);
      }
    }
  }
}

__global__ __launch_bounds__(1024) void k_proj(KParams P) {
  __shared__ __align__(16) char smem[159744];
  char* combB = smem;                                       // 98304
  char* hlB   = smem + 98304;                               // 18432
  char* XB    = smem + 116736;                              // 24576
  unsigned short* wlB = (unsigned short*)(smem + 141312);   // 13824
  float* wgl  = (float*)(smem + 155136);                    // 4608

  const int t  = threadIdx.x;
  const int b  = blockIdx.x >> 3;
  const int h0 = (blockIdx.x & 7) * 4;

  for (int i = t; i < 1152; i += 1024)
    wgl[i] = P.wg[(size_t)(i/C_)*(B_*C_) + b*C_ + (i % C_)];
  for (int i = t; i < 6912; i += 1024) {
    int s = i / 2304, r = i - s*2304, mi2 = r / 1152, rr = r - mi2*1152;
    wlB[i] = f2bf(P.mw1[s][mi2*1152 + rr]);                 // [(s*2+mi)*1152 + c*12 + j]
  }
  for (int i = t*4; i < 12288; i += 4096) {
    int c = i >> 7, pix = i & 127;
    float4 v = *(const float4*)&P.x[(size_t)(b*C_ + c)*HW + h0*32 + pix];
    unsigned lo = (unsigned)f2bf(v.x) | ((unsigned)f2bf(v.y) << 16);
    unsigned hi = (unsigned)f2bf(v.z) | ((unsigned)f2bf(v.w) << 16);
    *(uint2*)(XB + c*256 + pix*2) = make_uint2(lo, hi);
  }
  __syncthreads();

#pragma unroll 1
  for (int mi = 0; mi < 2; ++mi) {
    if (t < 512) {
      // ---- layer1(mi): waves 0-7 ----
      const int oct = t & 15, cq = (t >> 4) & 3, sjg = t >> 6;
      const int nsj = (sjg < 4) ? 5 : 4;
      const int sj0 = (sjg < 4) ? sjg*5 : 20 + (sjg - 4)*4;
      int wbase[5]; float bias[5];
#pragma unroll
      for (int u = 0; u < 5; ++u) {
        int sj = sj0 + ((u < nsj) ? u : 0);
        int s = sj / 12, jj = sj - s*12;
        wbase[u] = (s*2 + mi)*1152 + jj;
        bias[u] = P.mb1[s][mi*12 + jj];
      }
      float h[5][8];
#pragma unroll
      for (int u = 0; u < 5; ++u)
#pragma unroll
        for (int p = 0; p < 8; ++p) h[u][p] = 0.f;
      for (int c = cq*24; c < cq*24 + 24; ++c) {
        const us8v xv = *(const us8v*)(XB + c*256 + oct*16);
        float xf[8];
#pragma unroll
        for (int p = 0; p < 8; ++p) xf[p] = bf2f(xv[p]);
#pragma unroll
        for (int u = 0; u < 5; ++u) {
          if (u < nsj) {
            const float w = bf2f(wlB[wbase[u] + c*12]);
#pragma unroll
            for (int p = 0; p < 8; ++p) h[u][p] += xf[p]*w;
          }
        }
      }
#pragma unroll
      for (int u = 0; u < 5; ++u)
#pragma unroll
        for (int p = 0; p < 8; ++p) {
          h[u][p] += __shfl_xor(h[u][p], 16, 64);
          h[u][p] += __shfl_xor(h[u][p], 32, 64);
        }
      if (cq == 0) {
#pragma unroll
        for (int u = 0; u < 5; ++u) {
          if (u < nsj) {
            us8v o;
#pragma unroll
            for (int p = 0; p < 8; ++p) o[p] = f2bf(gelu_exact(h[u][p] + bias[u]));
            *(us8v*)(hlB + (mi*36 + sj0 + u)*256 + oct*16) = o;
          }
        }
      }
    } else {
      // ---- conv half mi: waves 8-15 ----
      if (mi == 0) conv_phase2<0>(P, b, h0, combB, wgl, t - 512);
      else         conv_phase2<1>(P, b, h0, combB, wgl, t - 512);
    }
    __syncthreads();
    if (mi == 0) {
      for (int i = t*4; i < 12288; i += 4096) {
        int c = i >> 7, pix = i & 127;
        float4 v = *(const float4*)&P.x[(size_t)(b*C_ + 192 + c)*HW + h0*32 + pix];
        unsigned lo = (unsigned)f2bf(v.x) | ((unsigned)f2bf(v.y) << 16);
        unsigned hi = (unsigned)f2bf(v.z) | ((unsigned)f2bf(v.w) << 16);
        *(uint2*)(XB + c*256 + pix*2) = make_uint2(lo, hi);
      }
      __syncthreads();
    }
  }

  // stage w2 (overwrites w1 region)
  for (int i = t; i < 6912; i += 1024) {
    int s = i / 2304, r = i - s*2304, mi2 = r / 1152, rr = r - mi2*1152;
    wlB[i] = f2bf(P.mw2[s][mi2*1152 + rr]);                 // [(s*2+mi)*1152 + j*96 + c]
  }
  __syncthreads();

  // ---- layer2 + gate -> comb (MLP channels), all 1024 threads ----
  {
    const int ct = t & 31, pt = (t >> 5) & 15, mi = t >> 9;
    const int c0 = ct*3, pix0 = pt*8;
    float wgc[3][3];
#pragma unroll
    for (int s = 0; s < 3; ++s)
#pragma unroll
      for (int i = 0; i < 3; ++i) wgc[s][i] = wgl[s*C_ + mi*192 + c0 + i];
    float acc[3][8];
#pragma unroll
    for (int i = 0; i < 3; ++i) {
      float ai = 0.f;
#pragma unroll
      for (int s = 0; s < 3; ++s) ai += wgc[s][i] * P.mb2[s][mi*96 + c0 + i];
#pragma unroll
      for (int p = 0; p < 8; ++p) acc[i][p] = ai;
    }
#pragma unroll
    for (int s = 0; s < 3; ++s)
#pragma unroll
      for (int jj = 0; jj < 12; ++jj) {
        const us8v hv = *(const us8v*)(hlB + (mi*36 + s*12 + jj)*256 + pix0*2);
        float hf[8];
#pragma unroll
        for (int p = 0; p < 8; ++p) hf[p] = bf2f(hv[p]);
        const unsigned short* wp = wlB + (s*2 + mi)*1152 + jj*96 + c0;
        float gw[3];
#pragma unroll
        for (int i = 0; i < 3; ++i) gw[i] = bf2f(wp[i]) * wgc[s][i];
#pragma unroll
        for (int i = 0; i < 3; ++i)
#pragma unroll
          for (int p = 0; p < 8; ++p) acc[i][p] += gw[i]*hf[p];
      }
#pragma unroll
    for (int i = 0; i < 3; ++i)
#pragma unroll
      for (int p = 0; p < 8; ++p) {
        const int pix = pix0 + p;
        const int kp2 = mi*96 + c0 + i;
        const int off = pix*768 + ((kp2*2) ^ ((pix & 15) << 4));
        *(unsigned short*)(combB + off) = f2bf(acc[i][p]);
      }
  }
  __syncthreads();

  // ---- MFMA GEMM: out[pix][d] = comb[pix][k'] * pwT[d][k'], 16 waves 2Mx8N ----
  {
    const int lane = t & 63, wv = t >> 6;
    const int wm = wv & 1, wn = wv >> 1;
    const int l15 = lane & 15, l4 = lane >> 4;
    f32x4 acc[4][3];
#pragma unroll
    for (int mt = 0; mt < 4; ++mt)
#pragma unroll
      for (int nt = 0; nt < 3; ++nt) acc[mt][nt] = (f32x4){0.f,0.f,0.f,0.f};
    const char* pwTb = (const char*)P.pwT;
#pragma unroll 2
    for (int ks = 0; ks < 12; ++ks) {
      const int k0 = ks*32 + l4*8;
      s16x8 af[4], bfr[3];
#pragma unroll
      for (int mt = 0; mt < 4; ++mt) {
        const int m = wm*64 + mt*16 + l15;
        af[mt] = *(const s16x8*)(combB + m*768 + ((2*k0) ^ ((m & 15) << 4)));
      }
#pragma unroll
      for (int nt = 0; nt < 3; ++nt) {
        const int d = wn*48 + nt*16 + l15;
        bfr[nt] = *(const s16x8*)(pwTb + (size_t)d*768 + 2*k0);
      }
#pragma unroll
      for (int mt = 0; mt < 4; ++mt)
#pragma unroll
        for (int nt = 0; nt < 3; ++nt)
          acc[mt][nt] = __builtin_amdgcn_mfma_f32_16x16x32_bf16(af[mt], bfr[nt], acc[mt][nt], 0, 0, 0);
    }
#pragma unroll
    for (int nt = 0; nt < 3; ++nt) {
      const int d = wn*48 + nt*16 + l15;
      const float pbv = P.pb[d];
#pragma unroll
      for (int mt = 0; mt < 4; ++mt) {
        const int pix = wm*64 + mt*16 + l4*4;
        float4 o;
        o.x = acc[mt][nt][0] + pbv;
        o.y = acc[mt][nt][1] + pbv;
        o.z = acc[mt][nt][2] + pbv;
        o.w = acc[mt][nt][3] + pbv;
        *(float4*)&P.out[(size_t)(b*C_ + d)*HW + (h0 + (pix >> 5))*32 + (pix & 31)] = o;
      }
    }
  }
}

// ---------------------------------------------------------------------------
extern "C" void kernel_launch(void* const* d_in, const int* in_sizes, int n_in,
                              void* d_out, int out_size, void* d_ws, size_t ws_size,
                              hipStream_t stream) {
  KParams P;
  P.x = (const float*)d_in[0];
  for (int s = 0; s < 3; ++s) {
    const int base = 1 + s * 6;
    P.mw1[s] = (const float*)d_in[base + 0];
    P.mb1[s] = (const float*)d_in[base + 1];
    P.mw2[s] = (const float*)d_in[base + 2];
    P.mb2[s] = (const float*)d_in[base + 3];
    P.cw[s]  = (const float*)d_in[base + 4];
    P.cb[s]  = (const float*)d_in[base + 5];
  }
  P.fw1 = (const float*)d_in[19]; P.fb1 = (const float*)d_in[20];
  P.fw2 = (const float*)d_in[21]; P.fb2 = (const float*)d_in[22];
  P.pw  = (const float*)d_in[23]; P.pb  = (const float*)d_in[24];
  float* w = (float*)d_ws;
  P.wg     = w;                              // 36864 floats
  P.H_part = w + 36864;                      // 18432
  P.cvA    = w + 55296;                      // 30720
  P.ext    = w + 86016;                      // 122880
  P.pwT    = (unsigned short*)(w + 208896);  // 147456 ushorts
  P.out = (float*)d_out;

  hipMemsetAsync((char*)d_ws + 55296*sizeof(float), 0, 30720*sizeof(float), stream);
  k_prep<<<144, 256, 0, stream>>>(P);
  k_sum <<<1024, 256, 0, stream>>>(P);
  k_gate<<<32, 256, 0, stream>>>(P);
  k_proj<<<256, 1024, 0, stream>>>(P);
}

// Round 4
// 289.771 us; speedup vs baseline: 1.0521x; 1.0521x over previous
//
#include <hip/hip_runtime.h>
#include <math.h>

#define B_  32
#define C_  384
#define HW  1024

typedef float          f32x4 __attribute__((ext_vector_type(4)));
typedef short          s16x8 __attribute__((ext_vector_type(8)));
typedef unsigned short us8v  __attribute__((ext_vector_type(8)));

#define SWZ(pix) ((((pix) ^ ((pix) >> 4)) & 15) << 4)

struct KParams {
  const float* x;
  const float* mw1[3]; const float* mb1[3]; const float* mw2[3]; const float* mb2[3];
  const float* cw[3];  const float* cb[3];
  const float* fw1; const float* fb1; const float* fw2; const float* fb2;
  const float* pw;  const float* pb;
  float* wg;            // [3][B][C]
  float* H_part;        // [B][2][8][36]
  float* cvA;           // [B][2][5][96]  {T, C0, C1, C30, C31} (atomic-accumulated)
  float* ext;           // [B][2][2][10][96]
  unsigned short* pwT;  // [384 d][384 k'] bf16, k' permuted
  float* out;
};

__device__ __forceinline__ float gelu_exact(float v) {
  return 0.5f * v * (1.0f + erff(v * 0.70710678118654752440f));
}
__device__ __forceinline__ unsigned short f2bf(float f) {
  unsigned u = __float_as_uint(f);
  u += 0x7FFFu + ((u >> 16) & 1u);
  return (unsigned short)(u >> 16);
}
__device__ __forceinline__ float bf2f(unsigned short h) {
  return __uint_as_float(((unsigned)h) << 16);
}

// ---------------------------------------------------------------------------
// conv window for k_proj recompute (verified round-2 code)
// ---------------------------------------------------------------------------
template<int HALF>
__device__ __forceinline__ void conv_strip(const float* xc, int h0, int row,
                                           float w1t, const float* w3, const float* w5,
                                           float* y0, float* y1, float* y2) {
#pragma unroll
  for (int p = 0; p < 16; ++p) { y0[p] = 0.f; y1[p] = 0.f; y2[p] = 0.f; }
#pragma unroll
  for (int dy = 0; dy < 5; ++dy) {
    const int hr = h0 + row - 2 + dy;
    float win[20];
    if (hr >= 0 && hr < 32) {
#pragma unroll
      for (int u = 0; u < 5; ++u)
        *(float4*)&win[u*4] = *(const float4*)&xc[hr*32 + HALF*12 + u*4];
    } else {
#pragma unroll
      for (int u = 0; u < 20; ++u) win[u] = 0.f;
    }
#pragma unroll
    for (int dx = 0; dx < 5; ++dx) {
      const float w = w5[dy*5 + dx];
#pragma unroll
      for (int p = 0; p < 16; ++p) {
        const int ri = p + dx - 2 + HALF*4;
        if (ri >= 0 && ri < 20) y2[p] += win[ri] * w;
      }
    }
    if (dy >= 1 && dy <= 3) {
#pragma unroll
      for (int dx = 0; dx < 3; ++dx) {
        const float w = w3[(dy-1)*3 + dx];
#pragma unroll
        for (int p = 0; p < 16; ++p) {
          const int ri = p + dx - 1 + HALF*4;
          if (ri >= 0 && ri < 20) y1[p] += win[ri] * w;
        }
      }
      if (dy == 2) {
#pragma unroll
        for (int p = 0; p < 16; ++p) y0[p] = win[p + HALF*4] * w1t;
      }
    }
  }
}

// ---------------------------------------------------------------------------
// k_work: blocks 0..1023 = sums (b x 32 sub); blocks 1024..1167 = pwT prep
// ---------------------------------------------------------------------------
__global__ __launch_bounds__(256, 2) void k_work(KParams P) {
  __shared__ __align__(16) char sm[49152 + 13824 + 256];
  const int bid = blockIdx.x;
  const int t = threadIdx.x;

  if (bid >= 1024) {
    // ---- pwT transpose: pwT[d][k'] = bf16(pw[gc(k')][d]) ----
    const int pbk = bid - 1024;
    float (*tile)[33] = (float(*)[33])sm;
    const int td = pbk % 12, tc = pbk / 12;
    const int j = t & 31, i0 = t >> 5;
    const int gcoff = (tc < 3) ? 0 : (tc < 6 ? 96 : (tc < 9 ? -96 : 0));
    for (int i = i0; i < 32; i += 8)
      tile[i][j] = P.pw[(size_t)(tc*32 + i + gcoff)*C_ + td*32 + j];
    __syncthreads();
    for (int i = i0; i < 32; i += 8)
      P.pwT[(size_t)(td*32 + i)*C_ + tc*32 + j] = f2bf(tile[j][i]);
    return;
  }

  const int b = bid >> 5, sub = bid & 31;
  if (sub < 16) {
    const int mi = sub >> 3, q = sub & 7;
    const int h0 = q * 4;
    float* Xl  = (float*)sm;                     // [96][128]
    float* w1l = (float*)(sm + 49152);           // [s][c][j]
    float* Hl  = (float*)(sm + 49152 + 13824);   // [36]
    for (int i = t; i < 3456; i += 256) {
      int s = i / 1152, r = i - s*1152;
      w1l[i] = P.mw1[s][mi*1152 + r];
    }
    for (int i = t*4; i < 12288; i += 1024) {
      int c = i >> 7, pix = i & 127;
      *(float4*)&Xl[i] = *(const float4*)&P.x[(size_t)(b*C_ + mi*192 + c)*HW + h0*32 + pix];
    }
    __syncthreads();
    const int quad = t & 31, sjg = t >> 6;
    const int cq = (t >> 5) & 1;
    const int sj0 = sjg * 9;
    float h[9][4];
#pragma unroll
    for (int u = 0; u < 9; ++u) { h[u][0]=0.f; h[u][1]=0.f; h[u][2]=0.f; h[u][3]=0.f; }
    int wbase[9];
#pragma unroll
    for (int u = 0; u < 9; ++u) {
      int sj = sj0 + u, s = sj / 12, jj = sj % 12;
      wbase[u] = s*1152 + jj;
    }
    for (int c = cq*48; c < cq*48 + 48; ++c) {
      const float4 xv = *(const float4*)&Xl[c*128 + quad*4];
#pragma unroll
      for (int u = 0; u < 9; ++u) {
        const float w = w1l[wbase[u] + c*12];
        h[u][0] += xv.x*w; h[u][1] += xv.y*w; h[u][2] += xv.z*w; h[u][3] += xv.w*w;
      }
    }
#pragma unroll
    for (int u = 0; u < 9; ++u)
#pragma unroll
      for (int p = 0; p < 4; ++p) h[u][p] += __shfl_xor(h[u][p], 32, 64);
    float hs[9];
#pragma unroll
    for (int u = 0; u < 9; ++u) {
      int sj = sj0 + u, s = sj / 12, jj = sj % 12;
      const float bias = P.mb1[s][mi*12 + jj];
      float sum = 0.f;
#pragma unroll
      for (int p = 0; p < 4; ++p) sum += gelu_exact(h[u][p] + bias);
#pragma unroll
      for (int m = 16; m >= 1; m >>= 1) sum += __shfl_xor(sum, m, 64);
      hs[u] = sum;
    }
    if ((t & 63) == 0) {
#pragma unroll
      for (int u = 0; u < 9; ++u) Hl[sj0 + u] = hs[u];
    }
    __syncthreads();
    if (t < 36) P.H_part[(size_t)((b*2 + mi)*8 + q)*36 + t] = Hl[t];
  } else {
    // ---- conv border-stat block ----
    const int s2 = sub - 16;
    const int gi = s2 >> 3, q = s2 & 7;
    const int h0 = q * 4;
    const int lane = t & 63, wv = t >> 6;
    const int gcbase = (2*gi + 1) * 96;
    for (int i = 0; i < 24; ++i) {
      const int cc = wv*24 + i;
      const float* xc = P.x + (size_t)(b*C_ + gcbase + cc)*HW + h0*32;
      const float2 v = *(const float2*)(xc + 2*lane);
      const float t2 = v.x + v.y;
      float T = t2;
      T += __shfl_xor(T, 1, 64);  T += __shfl_xor(T, 2, 64);
      T += __shfl_xor(T, 4, 64);  T += __shfl_xor(T, 8, 64);
      T += __shfl_xor(T, 16, 64); T += __shfl_xor(T, 32, 64);
      float c0  = ((lane & 15) == 0)  ? v.x : 0.f;
      float c1  = ((lane & 15) == 0)  ? v.y : 0.f;
      float c30 = ((lane & 15) == 15) ? v.x : 0.f;
      float c31 = ((lane & 15) == 15) ? v.y : 0.f;
      c0  += __shfl_xor(c0, 16, 64);  c0  += __shfl_xor(c0, 32, 64);
      c1  += __shfl_xor(c1, 16, 64);  c1  += __shfl_xor(c1, 32, 64);
      c30 += __shfl_xor(c30, 16, 64); c30 += __shfl_xor(c30, 32, 64);
      c31 += __shfl_xor(c31, 16, 64); c31 += __shfl_xor(c31, 32, 64);
      if (lane == 0) {
        float* A = &P.cvA[(size_t)(b*2 + gi)*5*96 + cc];
        atomicAdd(A + 0*96, T);   atomicAdd(A + 1*96, c0);
        atomicAdd(A + 2*96, c1);  atomicAdd(A + 3*96, c30);
        atomicAdd(A + 4*96, c31);
      }
      if (q == 0 || q == 7) {
        float r = t2;
        r += __shfl_xor(r, 1, 64); r += __shfl_xor(r, 2, 64);
        r += __shfl_xor(r, 4, 64); r += __shfl_xor(r, 8, 64);
        const int e  = (q == 0) ? 0 : 1;
        const int lo = (q == 0) ? 0 : 32;
        const float Ra  = __shfl(r,   lo,      64), Rb  = __shfl(r,   lo + 16, 64);
        const float p00 = __shfl(v.x, lo,      64), p01 = __shfl(v.y, lo,      64);
        const float p0a = __shfl(v.x, lo + 15, 64), p0b = __shfl(v.y, lo + 15, 64);
        const float p10 = __shfl(v.x, lo + 16, 64), p11 = __shfl(v.y, lo + 16, 64);
        const float p1a = __shfl(v.x, lo + 31, 64), p1b = __shfl(v.y, lo + 31, 64);
        if (lane == 0) {
          float* E = &P.ext[((size_t)(b*2 + gi)*2 + e)*10*96 + cc];
          E[0*96] = Ra;  E[1*96] = Rb;
          E[2*96] = p00; E[3*96] = p01; E[4*96] = p0a; E[5*96] = p0b;
          E[6*96] = p10; E[7*96] = p11; E[8*96] = p1a; E[9*96] = p1b;
        }
      }
    }
  }
}

// ---------------------------------------------------------------------------
// k_gate: finish sums -> a[c] -> fusion MLP -> softmax. grid=B, 512 threads.
// ---------------------------------------------------------------------------
__global__ __launch_bounds__(512) void k_gate(KParams P) {
  const int b = blockIdx.x, t = threadIdx.x;
  __shared__ float am[C_], g1p[4][96], g1v[96], Hs[2][36];
  for (int i = t; i < 72; i += 512) {
    int mi = i / 36, sj = i % 36;
    float s = 0.f;
    for (int q = 0; q < 8; ++q) s += P.H_part[(size_t)((b*2+mi)*8 + q)*36 + sj];
    Hs[mi][sj] = s * (1.0f/1024.0f);
  }
  __syncthreads();
  if (t < 192) {
    // MLP-chunk means via layer 2
    const int mi = t / 96, cc = t % 96;
    float a = 0.f;
    for (int s = 0; s < 3; ++s) {
      float y = P.mb2[s][mi*96 + cc];
      for (int jj = 0; jj < 12; ++jj) y += Hs[mi][s*12+jj] * P.mw2[s][mi*1152 + jj*96 + cc];
      a += y;
    }
    am[mi*192 + cc] = a;
  } else if (t < 384) {
    // conv-chunk means via border stats
    const int i = t - 192;
    const int gi = i / 96, cc = i % 96;
    const float* A  = &P.cvA[(size_t)(b*2 + gi)*5*96 + cc];
    const float T   = A[0*96];
    const float C0  = A[1*96], C1  = A[2*96], C30 = A[3*96], C31 = A[4*96];
    const float* E0 = &P.ext[((size_t)(b*2 + gi)*2 + 0)*10*96 + cc];
    const float* E1 = &P.ext[((size_t)(b*2 + gi)*2 + 1)*10*96 + cc];
    const float R0  = E0[0*96], R1  = E0[1*96];
    const float a00 = E0[2*96], a01 = E0[3*96], a0a = E0[4*96], a0b = E0[5*96];
    const float a10 = E0[6*96], a11 = E0[7*96], a1a = E0[8*96], a1b = E0[9*96];
    const float R30 = E1[0*96], R31 = E1[1*96];
    const float b00 = E1[2*96], b01 = E1[3*96], b0a = E1[4*96], b0b = E1[5*96];
    const float b10 = E1[6*96], b11 = E1[7*96], b1a = E1[8*96], b1b = E1[9*96];
    const float ER[5]   = {R30+R31, R31, 0.f, R0, R0+R1};
    const float EC[5]   = {C30+C31, C31, 0.f, C0, C0+C1};
    const float cr0[5]  = {a0a+a0b, a0b, 0.f, a00, a00+a01};
    const float cr1[5]  = {a1a+a1b, a1b, 0.f, a10, a10+a11};
    const float cr30[5] = {b0a+b0b, b0b, 0.f, b00, b00+b01};
    const float cr31[5] = {b1a+b1b, b1b, 0.f, b10, b10+b11};
    const int gcl = gi*96 + cc;
    float sum = P.cw[0][gcl] * T;
#pragma unroll
    for (int dy = 0; dy < 3; ++dy)
#pragma unroll
      for (int dx = 0; dx < 3; ++dx) {
        const int s = dy - 1, u = dx - 1;
        float xc_ = 0.f;
        if (s == 1)  xc_ = cr0[u+2];
        if (s == -1) xc_ = cr31[u+2];
        sum += P.cw[1][gcl*9 + dy*3 + dx] * (T - ER[s+2] - EC[u+2] + xc_);
      }
#pragma unroll
    for (int dy = 0; dy < 5; ++dy)
#pragma unroll
      for (int dx = 0; dx < 5; ++dx) {
        const int s = dy - 2, u = dx - 2;
        float xc_ = 0.f;
        if (s == 1)  xc_ = cr0[u+2];
        if (s == 2)  xc_ = cr0[u+2] + cr1[u+2];
        if (s == -1) xc_ = cr31[u+2];
        if (s == -2) xc_ = cr30[u+2] + cr31[u+2];
        sum += P.cw[2][gcl*25 + dy*5 + dx] * (T - ER[s+2] - EC[u+2] + xc_);
      }
    am[(2*gi+1)*96 + cc] = sum * (1.0f/1024.0f)
                         + P.cb[0][gcl] + P.cb[1][gcl] + P.cb[2][gcl];
  }
  __syncthreads();
  if (t < 384) {
    const int quarter = t / 96, jj = t % 96;
    float acc = 0.f;
    for (int c = quarter*96; c < quarter*96 + 96; ++c) acc += am[c] * P.fw1[c*96 + jj];
    g1p[quarter][jj] = acc;
  }
  __syncthreads();
  if (t < 96) g1v[t] = gelu_exact(g1p[0][t] + g1p[1][t] + g1p[2][t] + g1p[3][t] + P.fb1[t]);
  __syncthreads();
  if (t < 384) {
    const int c = t;
    float l0 = P.fb2[c*3+0], l1 = P.fb2[c*3+1], l2 = P.fb2[c*3+2];
    for (int jj = 0; jj < 96; ++jj) {
      const float g = g1v[jj];
      const float* f = P.fw2 + jj*1152 + c*3;
      l0 += g*f[0]; l1 += g*f[1]; l2 += g*f[2];
    }
    const float m = fmaxf(l0, fmaxf(l1, l2));
    const float e0 = expf(l0-m), e1 = expf(l1-m), e2 = expf(l2-m);
    const float inv = 1.0f/(e0+e1+e2);
    P.wg[0*(B_*C_) + b*C_ + c] = e0*inv;
    P.wg[1*(B_*C_) + b*C_ + c] = e1*inv;
    P.wg[2*(B_*C_) + b*C_ + c] = e2*inv;
  }
}

// ---------------------------------------------------------------------------
// k_proj: grid = b(32) x rowquad(8), 1024 threads (16 waves), cap VGPR=128.
// ---------------------------------------------------------------------------
template<int HALF>
__device__ __forceinline__ void conv_phase2(const KParams& P, int b, int h0,
                                            char* combB, const float* wgl, int tt) {
  for (int it = 0; it < 2; ++it) {
    const int task = tt + 512*it;
    if (task < 768) {
      const int row = task & 3, c192 = task >> 2;
      const int gi = c192 / 96, cc = c192 - gi*96;
      const int gcl = gi*96 + cc;
      const int gc = (2*gi + 1)*96 + cc;
      const int kp = 192 + gi*96 + cc;
      const float* xc = P.x + (size_t)(b*C_ + gc)*HW;
      const float w1t = P.cw[0][gcl];
      float w3[9], w5[25];
#pragma unroll
      for (int k2 = 0; k2 < 9; ++k2)  w3[k2] = P.cw[1][gcl*9 + k2];
#pragma unroll
      for (int k2 = 0; k2 < 25; ++k2) w5[k2] = P.cw[2][gcl*25 + k2];
      float y0[16], y1[16], y2[16];
      conv_strip<HALF>(xc, h0, row, w1t, w3, w5, y0, y1, y2);
      const float g0 = wgl[0*C_ + gc], g1 = wgl[1*C_ + gc], g2 = wgl[2*C_ + gc];
      const float cbg = g0*P.cb[0][gcl] + g1*P.cb[1][gcl] + g2*P.cb[2][gcl];
#pragma unroll
      for (int p = 0; p < 16; ++p) {
        const float v = g0*y0[p] + g1*y1[p] + g2*y2[p] + cbg;
        const int pix = row*32 + HALF*16 + p;
        const int off = pix*768 + ((kp*2) ^ SWZ(pix));
        *(unsigned short*)(combB + off) = f2bf(v);
      }
    }
  }
}

__global__ __launch_bounds__(1024, 4) void k_proj(KParams P) {
  __shared__ __align__(16) char smem[159744];
  char* combB = smem;                                       // 98304
  char* hlB   = smem + 98304;                               // 18432
  char* XB    = smem + 116736;                              // 24576
  unsigned short* wlB = (unsigned short*)(smem + 141312);   // 13824
  float* wgl  = (float*)(smem + 155136);                    // 4608

  const int t  = threadIdx.x;
  const int rb = (blockIdx.x & 7) * 32 + (blockIdx.x >> 3);  // XCD-aware swizzle
  const int b  = rb >> 3;
  const int h0 = (rb & 7) * 4;

  for (int i = t; i < 1152; i += 1024)
    wgl[i] = P.wg[(size_t)(i/C_)*(B_*C_) + b*C_ + (i % C_)];
  // stage w1 j-major: wlB[(s*2+mi)*1152 + jj*96 + c]
  for (int i = t; i < 6912; i += 1024) {
    int s = i / 2304, r = i - s*2304, mi2 = r / 1152, rr = r - mi2*1152;
    int c = rr / 12, jj = rr - c*12;
    wlB[(s*2 + mi2)*1152 + jj*96 + c] = f2bf(P.mw1[s][mi2*1152 + rr]);
  }
  for (int i = t*4; i < 12288; i += 4096) {
    int c = i >> 7, pix = i & 127;
    float4 v = *(const float4*)&P.x[(size_t)(b*C_ + c)*HW + h0*32 + pix];
    unsigned lo = (unsigned)f2bf(v.x) | ((unsigned)f2bf(v.y) << 16);
    unsigned hi = (unsigned)f2bf(v.z) | ((unsigned)f2bf(v.w) << 16);
    *(uint2*)(XB + c*256 + pix*2) = make_uint2(lo, hi);
  }
  __syncthreads();

#pragma unroll 1
  for (int mi = 0; mi < 2; ++mi) {
    if (t < 512) {
      // ---- layer1(mi): waves 0-7, wave w owns 4-5 j's, lane l owns pix 2l,2l+1
      const int w = t >> 6, l = t & 63;
      const int nsj = (w < 4) ? 5 : 4;
      const int sj0 = (w < 4) ? w*5 : 20 + (w - 4)*4;
      int wbase[5]; float bias[5];
#pragma unroll
      for (int u = 0; u < 5; ++u) {
        int sj = sj0 + ((u < nsj) ? u : 0);
        int s = sj / 12, jj = sj - s*12;
        wbase[u] = (s*2 + mi)*1152 + jj*96;
        bias[u] = P.mb1[s][mi*12 + jj];
      }
      float h[5][2];
#pragma unroll
      for (int u = 0; u < 5; ++u) { h[u][0] = 0.f; h[u][1] = 0.f; }
      for (int c0 = 0; c0 < 96; c0 += 8) {
        us8v wv8[5];
#pragma unroll
        for (int u = 0; u < 5; ++u)
          wv8[u] = *(const us8v*)(wlB + wbase[u] + c0);     // broadcast b128
#pragma unroll
        for (int cc = 0; cc < 8; ++cc) {
          const unsigned xp = *(const unsigned*)(XB + (c0 + cc)*256 + l*4);
          const float x0 = __uint_as_float(xp << 16);
          const float x1 = __uint_as_float(xp & 0xFFFF0000u);
#pragma unroll
          for (int u = 0; u < 5; ++u) {
            if (u < nsj) {
              const float wv = bf2f(wv8[u][cc]);
              h[u][0] += x0*wv; h[u][1] += x1*wv;
            }
          }
        }
      }
#pragma unroll
      for (int u = 0; u < 5; ++u) {
        if (u < nsj) {
          const unsigned o = (unsigned)f2bf(gelu_exact(h[u][0] + bias[u]))
                           | ((unsigned)f2bf(gelu_exact(h[u][1] + bias[u])) << 16);
          *(unsigned*)(hlB + (mi*36 + sj0 + u)*256 + l*4) = o;
        }
      }
    } else {
      // ---- conv half mi: waves 8-15 ----
      if (mi == 0) conv_phase2<0>(P, b, h0, combB, wgl, t - 512);
      else         conv_phase2<1>(P, b, h0, combB, wgl, t - 512);
    }
    __syncthreads();
    if (mi == 0) {
      for (int i = t*4; i < 12288; i += 4096) {
        int c = i >> 7, pix = i & 127;
        float4 v = *(const float4*)&P.x[(size_t)(b*C_ + 192 + c)*HW + h0*32 + pix];
        unsigned lo = (unsigned)f2bf(v.x) | ((unsigned)f2bf(v.y) << 16);
        unsigned hi = (unsigned)f2bf(v.z) | ((unsigned)f2bf(v.w) << 16);
        *(uint2*)(XB + c*256 + pix*2) = make_uint2(lo, hi);
      }
      __syncthreads();
    }
  }

  // stage w2 (overwrites w1 region; source already j-major)
  for (int i = t; i < 6912; i += 1024) {
    int s = i / 2304, r = i - s*2304, mi2 = r / 1152, rr = r - mi2*1152;
    wlB[(s*2 + mi2)*1152 + rr] = f2bf(P.mw2[s][mi2*1152 + rr]);
  }
  __syncthreads();

  // ---- layer2 + gate -> comb (MLP channels), all 1024 threads ----
  {
    const int ct = t & 31, pt = (t >> 5) & 15, mi = t >> 9;
    const int c0 = ct*3, pix0 = pt*8;
    float wgc[3][3];
#pragma unroll
    for (int s = 0; s < 3; ++s)
#pragma unroll
      for (int i = 0; i < 3; ++i) wgc[s][i] = wgl[s*C_ + mi*192 + c0 + i];
    float acc[3][8];
#pragma unroll
    for (int i = 0; i < 3; ++i) {
      float ai = 0.f;
#pragma unroll
      for (int s = 0; s < 3; ++s) ai += wgc[s][i] * P.mb2[s][mi*96 + c0 + i];
#pragma unroll
      for (int p = 0; p < 8; ++p) acc[i][p] = ai;
    }
#pragma unroll
    for (int s = 0; s < 3; ++s)
#pragma unroll
      for (int jj = 0; jj < 12; ++jj) {
        const us8v hv = *(const us8v*)(hlB + (mi*36 + s*12 + jj)*256 + pix0*2);
        float hf[8];
#pragma unroll
        for (int p = 0; p < 8; ++p) hf[p] = bf2f(hv[p]);
        const unsigned short* wp = wlB + (s*2 + mi)*1152 + jj*96 + c0;
        float gw[3];
#pragma unroll
        for (int i = 0; i < 3; ++i) gw[i] = bf2f(wp[i]) * wgc[s][i];
#pragma unroll
        for (int i = 0; i < 3; ++i)
#pragma unroll
          for (int p = 0; p < 8; ++p) acc[i][p] += gw[i]*hf[p];
      }
#pragma unroll
    for (int i = 0; i < 3; ++i)
#pragma unroll
      for (int p = 0; p < 8; ++p) {
        const int pix = pix0 + p;
        const int kp2 = mi*96 + c0 + i;
        const int off = pix*768 + ((kp2*2) ^ SWZ(pix));
        *(unsigned short*)(combB + off) = f2bf(acc[i][p]);
      }
  }
  __syncthreads();

  // ---- MFMA GEMM: out[pix][d] = comb[pix][k'] * pwT[d][k'], 16 waves 2Mx8N ----
  {
    const int lane = t & 63, wv = t >> 6;
    const int wm = wv & 1, wn = wv >> 1;
    const int l15 = lane & 15, l4 = lane >> 4;
    f32x4 acc[4][3];
#pragma unroll
    for (int mt = 0; mt < 4; ++mt)
#pragma unroll
      for (int nt = 0; nt < 3; ++nt) acc[mt][nt] = (f32x4){0.f,0.f,0.f,0.f};
    const char* pwTb = (const char*)P.pwT;
#pragma unroll 2
    for (int ks = 0; ks < 12; ++ks) {
      const int k0 = ks*32 + l4*8;
      s16x8 af[4], bfr[3];
#pragma unroll
      for (int mt = 0; mt < 4; ++mt) {
        const int m = wm*64 + mt*16 + l15;
        af[mt] = *(const s16x8*)(combB + m*768 + ((2*k0) ^ SWZ(m)));
      }
#pragma unroll
      for (int nt = 0; nt < 3; ++nt) {
        const int d = wn*48 + nt*16 + l15;
        bfr[nt] = *(const s16x8*)(pwTb + (size_t)d*768 + 2*k0);
      }
#pragma unroll
      for (int mt = 0; mt < 4; ++mt)
#pragma unroll
        for (int nt = 0; nt < 3; ++nt)
          acc[mt][nt] = __builtin_amdgcn_mfma_f32_16x16x32_bf16(af[mt], bfr[nt], acc[mt][nt], 0, 0, 0);
    }
#pragma unroll
    for (int nt = 0; nt < 3; ++nt) {
      const int d = wn*48 + nt*16 + l15;
      const float pbv = P.pb[d];
#pragma unroll
      for (int mt = 0; mt < 4; ++mt) {
        const int pix = wm*64 + mt*16 + l4*4;
        float4 o;
        o.x = acc[mt][nt][0] + pbv;
        o.y = acc[mt][nt][1] + pbv;
        o.z = acc[mt][nt][2] + pbv;
        o.w = acc[mt][nt][3] + pbv;
        *(float4*)&P.out[(size_t)(b*C_ + d)*HW + (h0 + (pix >> 5))*32 + (pix & 31)] = o;
      }
    }
  }
}

// ---------------------------------------------------------------------------
extern "C" void kernel_launch(void* const* d_in, const int* in_sizes, int n_in,
                              void* d_out, int out_size, void* d_ws, size_t ws_size,
                              hipStream_t stream) {
  KParams P;
  P.x = (const float*)d_in[0];
  for (int s = 0; s < 3; ++s) {
    const int base = 1 + s * 6;
    P.mw1[s] = (const float*)d_in[base + 0];
    P.mb1[s] = (const float*)d_in[base + 1];
    P.mw2[s] = (const float*)d_in[base + 2];
    P.mb2[s] = (const float*)d_in[base + 3];
    P.cw[s]  = (const float*)d_in[base + 4];
    P.cb[s]  = (const float*)d_in[base + 5];
  }
  P.fw1 = (const float*)d_in[19]; P.fb1 = (const float*)d_in[20];
  P.fw2 = (const float*)d_in[21]; P.fb2 = (const float*)d_in[22];
  P.pw  = (const float*)d_in[23]; P.pb  = (const float*)d_in[24];
  float* w = (float*)d_ws;
  P.wg     = w;                              // 36864 floats
  P.H_part = w + 36864;                      // 18432
  P.cvA    = w + 55296;                      // 30720
  P.ext    = w + 86016;                      // 122880
  P.pwT    = (unsigned short*)(w + 208896);  // 147456 ushorts
  P.out = (float*)d_out;

  hipMemsetAsync((char*)d_ws + 55296*sizeof(float), 0, 30720*sizeof(float), stream);
  k_work<<<1168, 256, 0, stream>>>(P);
  k_gate<<<32, 512, 0, stream>>>(P);
  k_proj<<<256, 1024, 0, stream>>>(P);
}

// Round 5
// 248.247 us; speedup vs baseline: 1.2280x; 1.1673x over previous
//
#include <hip/hip_runtime.h>
#include <math.h>

#define B_  32
#define C_  384
#define HW  1024

typedef float          f32x4 __attribute__((ext_vector_type(4)));
typedef short          s16x8 __attribute__((ext_vector_type(8)));
typedef unsigned short us8v  __attribute__((ext_vector_type(8)));

#define SWZ(pix) ((((pix) ^ ((pix) >> 4)) & 15) << 4)

struct KParams {
  const float* x;
  const float* mw1[3]; const float* mb1[3]; const float* mw2[3]; const float* mb2[3];
  const float* cw[3];  const float* cb[3];
  const float* fw1; const float* fb1; const float* fw2; const float* fb2;
  const float* pw;  const float* pb;
  float* wg;            // [3][B][C]
  float* H_part;        // [B][2][8][36]
  float* cvS;           // [B][2][8][5][96]  per-q conv stats (no atomics)
  float* ext;           // [B][2][2][10][96]
  unsigned short* pwT;  // [384 d][384 k'] bf16, k' permuted
  unsigned short* hl;   // [B][2][36][1024] bf16 per-pixel gelu(h)
  float* out;
};

__device__ __forceinline__ float gelu_exact(float v) {
  return 0.5f * v * (1.0f + erff(v * 0.70710678118654752440f));
}
__device__ __forceinline__ unsigned short f2bf(float f) {
  unsigned u = __float_as_uint(f);
  u += 0x7FFFu + ((u >> 16) & 1u);
  return (unsigned short)(u >> 16);
}
__device__ __forceinline__ float bf2f(unsigned short h) {
  return __uint_as_float(((unsigned)h) << 16);
}

// ---------------------------------------------------------------------------
// conv window (verified round-2 code)
// ---------------------------------------------------------------------------
template<int HALF>
__device__ __forceinline__ void conv_strip(const float* xc, int h0, int row,
                                           float w1t, const float* w3, const float* w5,
                                           float* y0, float* y1, float* y2) {
#pragma unroll
  for (int p = 0; p < 16; ++p) { y0[p] = 0.f; y1[p] = 0.f; y2[p] = 0.f; }
#pragma unroll
  for (int dy = 0; dy < 5; ++dy) {
    const int hr = h0 + row - 2 + dy;
    float win[20];
    if (hr >= 0 && hr < 32) {
#pragma unroll
      for (int u = 0; u < 5; ++u)
        *(float4*)&win[u*4] = *(const float4*)&xc[hr*32 + HALF*12 + u*4];
    } else {
#pragma unroll
      for (int u = 0; u < 20; ++u) win[u] = 0.f;
    }
#pragma unroll
    for (int dx = 0; dx < 5; ++dx) {
      const float w = w5[dy*5 + dx];
#pragma unroll
      for (int p = 0; p < 16; ++p) {
        const int ri = p + dx - 2 + HALF*4;
        if (ri >= 0 && ri < 20) y2[p] += win[ri] * w;
      }
    }
    if (dy >= 1 && dy <= 3) {
#pragma unroll
      for (int dx = 0; dx < 3; ++dx) {
        const float w = w3[(dy-1)*3 + dx];
#pragma unroll
        for (int p = 0; p < 16; ++p) {
          const int ri = p + dx - 1 + HALF*4;
          if (ri >= 0 && ri < 20) y1[p] += win[ri] * w;
        }
      }
      if (dy == 2) {
#pragma unroll
        for (int p = 0; p < 16; ++p) y0[p] = win[p + HALF*4] * w1t;
      }
    }
  }
}

// ---------------------------------------------------------------------------
// k_work: blocks 0..1023 = sums+hl (b x 32 sub); blocks 1024..1167 = pwT prep
// ---------------------------------------------------------------------------
__global__ __launch_bounds__(256, 2) void k_work(KParams P) {
  __shared__ __align__(16) char sm[49152 + 13824 + 256];
  const int bid = blockIdx.x;
  const int t = threadIdx.x;

  if (bid >= 1024) {
    const int pbk = bid - 1024;
    float (*tile)[33] = (float(*)[33])sm;
    const int td = pbk % 12, tc = pbk / 12;
    const int j = t & 31, i0 = t >> 5;
    const int gcoff = (tc < 3) ? 0 : (tc < 6 ? 96 : (tc < 9 ? -96 : 0));
    for (int i = i0; i < 32; i += 8)
      tile[i][j] = P.pw[(size_t)(tc*32 + i + gcoff)*C_ + td*32 + j];
    __syncthreads();
    for (int i = i0; i < 32; i += 8)
      P.pwT[(size_t)(td*32 + i)*C_ + tc*32 + j] = f2bf(tile[j][i]);
    return;
  }

  const int b = bid >> 5, sub = bid & 31;
  if (sub < 16) {
    // ---- MLP layer1: per-pixel gelu(h) -> hl (bf16) AND pixel-sum -> H_part
    const int mi = sub >> 3, q = sub & 7;
    const int h0 = q * 4;
    float* Xl  = (float*)sm;                     // [96][128]
    float* w1l = (float*)(sm + 49152);           // [s][c][j]
    float* Hl  = (float*)(sm + 49152 + 13824);   // [36]
    for (int i = t; i < 3456; i += 256) {
      int s = i / 1152, r = i - s*1152;
      w1l[i] = P.mw1[s][mi*1152 + r];
    }
    for (int i = t*4; i < 12288; i += 1024) {
      int c = i >> 7, pix = i & 127;
      *(float4*)&Xl[i] = *(const float4*)&P.x[(size_t)(b*C_ + mi*192 + c)*HW + h0*32 + pix];
    }
    __syncthreads();
    const int quad = t & 31, sjg = t >> 6;
    const int cq = (t >> 5) & 1;
    const int sj0 = sjg * 9;
    float h[9][4];
#pragma unroll
    for (int u = 0; u < 9; ++u) { h[u][0]=0.f; h[u][1]=0.f; h[u][2]=0.f; h[u][3]=0.f; }
    int wbase[9];
#pragma unroll
    for (int u = 0; u < 9; ++u) {
      int sj = sj0 + u, s = sj / 12, jj = sj % 12;
      wbase[u] = s*1152 + jj;
    }
    for (int c = cq*48; c < cq*48 + 48; ++c) {
      const float4 xv = *(const float4*)&Xl[c*128 + quad*4];
#pragma unroll
      for (int u = 0; u < 9; ++u) {
        const float w = w1l[wbase[u] + c*12];
        h[u][0] += xv.x*w; h[u][1] += xv.y*w; h[u][2] += xv.z*w; h[u][3] += xv.w*w;
      }
    }
#pragma unroll
    for (int u = 0; u < 9; ++u)
#pragma unroll
      for (int p = 0; p < 4; ++p) h[u][p] += __shfl_xor(h[u][p], 32, 64);
    float hs[9];
#pragma unroll
    for (int u = 0; u < 9; ++u) {
      int sj = sj0 + u, s = sj / 12, jj = sj % 12;
      const float bias = P.mb1[s][mi*12 + jj];
      float g[4];
#pragma unroll
      for (int p = 0; p < 4; ++p) g[p] = gelu_exact(h[u][p] + bias);
      if ((t & 63) < 32) {
        uint2 pk;
        pk.x = (unsigned)f2bf(g[0]) | ((unsigned)f2bf(g[1]) << 16);
        pk.y = (unsigned)f2bf(g[2]) | ((unsigned)f2bf(g[3]) << 16);
        *(uint2*)(P.hl + ((size_t)(b*2 + mi)*36 + sj)*1024 + q*128 + quad*4) = pk;
      }
      float sum = g[0] + g[1] + g[2] + g[3];
#pragma unroll
      for (int m = 16; m >= 1; m >>= 1) sum += __shfl_xor(sum, m, 64);
      hs[u] = sum;
    }
    if ((t & 63) == 0) {
#pragma unroll
      for (int u = 0; u < 9; ++u) Hl[sj0 + u] = hs[u];
    }
    __syncthreads();
    if (t < 36) P.H_part[(size_t)((b*2 + mi)*8 + q)*36 + t] = Hl[t];
  } else {
    // ---- conv border-stat block (per-q slot, no atomics) ----
    const int s2 = sub - 16;
    const int gi = s2 >> 3, q = s2 & 7;
    const int h0 = q * 4;
    const int lane = t & 63, wv = t >> 6;
    const int gcbase = (2*gi + 1) * 96;
    for (int i = 0; i < 24; ++i) {
      const int cc = wv*24 + i;
      const float* xc = P.x + (size_t)(b*C_ + gcbase + cc)*HW + h0*32;
      const float2 v = *(const float2*)(xc + 2*lane);
      const float t2 = v.x + v.y;
      float T = t2;
      T += __shfl_xor(T, 1, 64);  T += __shfl_xor(T, 2, 64);
      T += __shfl_xor(T, 4, 64);  T += __shfl_xor(T, 8, 64);
      T += __shfl_xor(T, 16, 64); T += __shfl_xor(T, 32, 64);
      float c0  = ((lane & 15) == 0)  ? v.x : 0.f;
      float c1  = ((lane & 15) == 0)  ? v.y : 0.f;
      float c30 = ((lane & 15) == 15) ? v.x : 0.f;
      float c31 = ((lane & 15) == 15) ? v.y : 0.f;
      c0  += __shfl_xor(c0, 16, 64);  c0  += __shfl_xor(c0, 32, 64);
      c1  += __shfl_xor(c1, 16, 64);  c1  += __shfl_xor(c1, 32, 64);
      c30 += __shfl_xor(c30, 16, 64); c30 += __shfl_xor(c30, 32, 64);
      c31 += __shfl_xor(c31, 16, 64); c31 += __shfl_xor(c31, 32, 64);
      if (lane == 0) {
        float* S = &P.cvS[(((size_t)(b*2 + gi)*8 + q)*5)*96 + cc];
        S[0*96] = T;   S[1*96] = c0;  S[2*96] = c1;
        S[3*96] = c30; S[4*96] = c31;
      }
      if (q == 0 || q == 7) {
        float r = t2;
        r += __shfl_xor(r, 1, 64); r += __shfl_xor(r, 2, 64);
        r += __shfl_xor(r, 4, 64); r += __shfl_xor(r, 8, 64);
        const int e  = (q == 0) ? 0 : 1;
        const int lo = (q == 0) ? 0 : 32;
        const float Ra  = __shfl(r,   lo,      64), Rb  = __shfl(r,   lo + 16, 64);
        const float p00 = __shfl(v.x, lo,      64), p01 = __shfl(v.y, lo,      64);
        const float p0a = __shfl(v.x, lo + 15, 64), p0b = __shfl(v.y, lo + 15, 64);
        const float p10 = __shfl(v.x, lo + 16, 64), p11 = __shfl(v.y, lo + 16, 64);
        const float p1a = __shfl(v.x, lo + 31, 64), p1b = __shfl(v.y, lo + 31, 64);
        if (lane == 0) {
          float* E = &P.ext[((size_t)(b*2 + gi)*2 + e)*10*96 + cc];
          E[0*96] = Ra;  E[1*96] = Rb;
          E[2*96] = p00; E[3*96] = p01; E[4*96] = p0a; E[5*96] = p0b;
          E[6*96] = p10; E[7*96] = p11; E[8*96] = p1a; E[9*96] = p1b;
        }
      }
    }
  }
}

// ---------------------------------------------------------------------------
// k_gate: finish sums -> a[c] -> fusion MLP -> softmax. grid=B, 512 threads.
// ---------------------------------------------------------------------------
__global__ __launch_bounds__(512) void k_gate(KParams P) {
  const int b = blockIdx.x, t = threadIdx.x;
  __shared__ float am[C_], g1p[4][96], g1v[96], Hs[2][36];
  for (int i = t; i < 72; i += 512) {
    int mi = i / 36, sj = i % 36;
    float s = 0.f;
    for (int q = 0; q < 8; ++q) s += P.H_part[(size_t)((b*2+mi)*8 + q)*36 + sj];
    Hs[mi][sj] = s * (1.0f/1024.0f);
  }
  __syncthreads();
  if (t < 192) {
    const int mi = t / 96, cc = t % 96;
    float a = 0.f;
    for (int s = 0; s < 3; ++s) {
      float y = P.mb2[s][mi*96 + cc];
      for (int jj = 0; jj < 12; ++jj) y += Hs[mi][s*12+jj] * P.mw2[s][mi*1152 + jj*96 + cc];
      a += y;
    }
    am[mi*192 + cc] = a;
  } else if (t < 384) {
    const int i = t - 192;
    const int gi = i / 96, cc = i % 96;
    const float* S0 = &P.cvS[(((size_t)(b*2 + gi)*8)*5)*96 + cc];
    float T = 0.f, C0 = 0.f, C1 = 0.f, C30 = 0.f, C31 = 0.f;
#pragma unroll
    for (int q = 0; q < 8; ++q) {
      const float* Sq = S0 + (size_t)q*5*96;
      T += Sq[0*96]; C0 += Sq[1*96]; C1 += Sq[2*96]; C30 += Sq[3*96]; C31 += Sq[4*96];
    }
    const float* E0 = &P.ext[((size_t)(b*2 + gi)*2 + 0)*10*96 + cc];
    const float* E1 = &P.ext[((size_t)(b*2 + gi)*2 + 1)*10*96 + cc];
    const float R0  = E0[0*96], R1  = E0[1*96];
    const float a00 = E0[2*96], a01 = E0[3*96], a0a = E0[4*96], a0b = E0[5*96];
    const float a10 = E0[6*96], a11 = E0[7*96], a1a = E0[8*96], a1b = E0[9*96];
    const float R30 = E1[0*96], R31 = E1[1*96];
    const float b00 = E1[2*96], b01 = E1[3*96], b0a = E1[4*96], b0b = E1[5*96];
    const float b10 = E1[6*96], b11 = E1[7*96], b1a = E1[8*96], b1b = E1[9*96];
    const float ER[5]   = {R30+R31, R31, 0.f, R0, R0+R1};
    const float EC[5]   = {C30+C31, C31, 0.f, C0, C0+C1};
    const float cr0[5]  = {a0a+a0b, a0b, 0.f, a00, a00+a01};
    const float cr1[5]  = {a1a+a1b, a1b, 0.f, a10, a10+a11};
    const float cr30[5] = {b0a+b0b, b0b, 0.f, b00, b00+b01};
    const float cr31[5] = {b1a+b1b, b1b, 0.f, b10, b10+b11};
    const int gcl = gi*96 + cc;
    float sum = P.cw[0][gcl] * T;
#pragma unroll
    for (int dy = 0; dy < 3; ++dy)
#pragma unroll
      for (int dx = 0; dx < 3; ++dx) {
        const int s = dy - 1, u = dx - 1;
        float xc_ = 0.f;
        if (s == 1)  xc_ = cr0[u+2];
        if (s == -1) xc_ = cr31[u+2];
        sum += P.cw[1][gcl*9 + dy*3 + dx] * (T - ER[s+2] - EC[u+2] + xc_);
      }
#pragma unroll
    for (int dy = 0; dy < 5; ++dy)
#pragma unroll
      for (int dx = 0; dx < 5; ++dx) {
        const int s = dy - 2, u = dx - 2;
        float xc_ = 0.f;
        if (s == 1)  xc_ = cr0[u+2];
        if (s == 2)  xc_ = cr0[u+2] + cr1[u+2];
        if (s == -1) xc_ = cr31[u+2];
        if (s == -2) xc_ = cr30[u+2] + cr31[u+2];
        sum += P.cw[2][gcl*25 + dy*5 + dx] * (T - ER[s+2] - EC[u+2] + xc_);
      }
    am[(2*gi+1)*96 + cc] = sum * (1.0f/1024.0f)
                         + P.cb[0][gcl] + P.cb[1][gcl] + P.cb[2][gcl];
  }
  __syncthreads();
  if (t < 384) {
    const int quarter = t / 96, jj = t % 96;
    float acc = 0.f;
    for (int c = quarter*96; c < quarter*96 + 96; ++c) acc += am[c] * P.fw1[c*96 + jj];
    g1p[quarter][jj] = acc;
  }
  __syncthreads();
  if (t < 96) g1v[t] = gelu_exact(g1p[0][t] + g1p[1][t] + g1p[2][t] + g1p[3][t] + P.fb1[t]);
  __syncthreads();
  if (t < 384) {
    const int c = t;
    float l0 = P.fb2[c*3+0], l1 = P.fb2[c*3+1], l2 = P.fb2[c*3+2];
    for (int jj = 0; jj < 96; ++jj) {
      const float g = g1v[jj];
      const float* f = P.fw2 + jj*1152 + c*3;
      l0 += g*f[0]; l1 += g*f[1]; l2 += g*f[2];
    }
    const float m = fmaxf(l0, fmaxf(l1, l2));
    const float e0 = expf(l0-m), e1 = expf(l1-m), e2 = expf(l2-m);
    const float inv = 1.0f/(e0+e1+e2);
    P.wg[0*(B_*C_) + b*C_ + c] = e0*inv;
    P.wg[1*(B_*C_) + b*C_ + c] = e1*inv;
    P.wg[2*(B_*C_) + b*C_ + c] = e2*inv;
  }
}

// ---------------------------------------------------------------------------
// k_proj: grid = 256 blocks x 512 thr. stage(hl,w2,wg) -> conv+layer2 -> GEMM
// LDS: comb 98304 | hlB 18432 | wlB 13824 | wgl 4608 = 135168 B
// ---------------------------------------------------------------------------
__global__ __launch_bounds__(512, 1) void k_proj(KParams P) {
  __shared__ __align__(16) char smem[135168];
  char* combB = smem;                                       // 98304
  char* hlB   = smem + 98304;                               // 18432
  unsigned short* wlB = (unsigned short*)(smem + 117120);   // wait offset
  float* wgl  = (float*)(smem + 130944);

  const int t  = threadIdx.x;
  const int rb = (blockIdx.x & 7) * 32 + (blockIdx.x >> 3);  // XCD-aware swizzle
  const int b  = rb >> 3;
  const int qv = rb & 7;
  const int h0 = qv * 4;

  // ---- stage: gates, w2 (j-major, direct layout), hl tile ----
  for (int i = t; i < 1152; i += 512)
    wgl[i] = P.wg[(size_t)(i/C_)*(B_*C_) + b*C_ + (i % C_)];
  for (int i = t; i < 6912; i += 512) {
    int s = i / 2304, r = i - s*2304;
    wlB[i] = f2bf(P.mw2[s][r]);    // layout [(s*2+mi)*1152 + jj*96 + c]
  }
  for (int i = t; i < 2304; i += 512) {
    const int sjmi = i >> 5, pg = i & 31;
    const uint2 v = *(const uint2*)(P.hl + ((size_t)(b*72 + sjmi))*1024 + qv*128 + pg*4);
    *(uint2*)(hlB + sjmi*256 + pg*8) = v;
  }
  __syncthreads();

  // ---- conv chunks -> comb (1536 tasks over 3 iters) ----
  for (int it = 0; it < 3; ++it) {
    const int tt = t + 512*it;
    const int hlf = (tt >= 768) ? 1 : 0;
    const int rem = tt - hlf*768;
    const int row = rem & 3, c192 = rem >> 2;
    const int gi = c192 / 96, cc = c192 - gi*96;
    const int gcl = gi*96 + cc;
    const int gc = (2*gi + 1)*96 + cc;
    const int kp = 192 + gi*96 + cc;
    const float* xc = P.x + (size_t)(b*C_ + gc)*HW;
    const float w1t = P.cw[0][gcl];
    float w3[9], w5[25];
#pragma unroll
    for (int k2 = 0; k2 < 9; ++k2)  w3[k2] = P.cw[1][gcl*9 + k2];
#pragma unroll
    for (int k2 = 0; k2 < 25; ++k2) w5[k2] = P.cw[2][gcl*25 + k2];
    float y0[16], y1[16], y2[16];
    if (hlf == 0) conv_strip<0>(xc, h0, row, w1t, w3, w5, y0, y1, y2);
    else          conv_strip<1>(xc, h0, row, w1t, w3, w5, y0, y1, y2);
    const float g0 = wgl[0*C_ + gc], g1 = wgl[1*C_ + gc], g2 = wgl[2*C_ + gc];
    const float cbg = g0*P.cb[0][gcl] + g1*P.cb[1][gcl] + g2*P.cb[2][gcl];
#pragma unroll
    for (int p = 0; p < 16; ++p) {
      const float v = g0*y0[p] + g1*y1[p] + g2*y2[p] + cbg;
      const int pix = row*32 + hlf*16 + p;
      const int off = pix*768 + ((kp*2) ^ SWZ(pix));
      *(unsigned short*)(combB + off) = f2bf(v);
    }
  }

  // ---- layer2 + gate -> comb (MLP channels) ----
  {
    const int ct = t & 15, pt = (t >> 4) & 15, mi = t >> 8;
    const int c0 = ct*6, pix0 = pt*8;
    float wgc[3][6];
#pragma unroll
    for (int s = 0; s < 3; ++s)
#pragma unroll
      for (int i = 0; i < 6; ++i) wgc[s][i] = wgl[s*C_ + mi*192 + c0 + i];
    float acc[6][8];
#pragma unroll
    for (int i = 0; i < 6; ++i) {
      float ai = 0.f;
#pragma unroll
      for (int s = 0; s < 3; ++s) ai += wgc[s][i] * P.mb2[s][mi*96 + c0 + i];
#pragma unroll
      for (int p = 0; p < 8; ++p) acc[i][p] = ai;
    }
#pragma unroll
    for (int s = 0; s < 3; ++s)
#pragma unroll
      for (int jj = 0; jj < 12; ++jj) {
        const us8v hv = *(const us8v*)(hlB + (mi*36 + s*12 + jj)*256 + pix0*2);
        float hf[8];
#pragma unroll
        for (int p = 0; p < 8; ++p) hf[p] = bf2f(hv[p]);
        const unsigned short* wp = wlB + (s*2 + mi)*1152 + jj*96 + c0;
        float gw[6];
#pragma unroll
        for (int i = 0; i < 6; ++i) gw[i] = bf2f(wp[i]) * wgc[s][i];
#pragma unroll
        for (int i = 0; i < 6; ++i)
#pragma unroll
          for (int p = 0; p < 8; ++p) acc[i][p] += gw[i]*hf[p];
      }
#pragma unroll
    for (int i = 0; i < 6; ++i)
#pragma unroll
      for (int p = 0; p < 8; ++p) {
        const int pix = pix0 + p;
        const int kp2 = mi*96 + c0 + i;
        const int off = pix*768 + ((kp2*2) ^ SWZ(pix));
        *(unsigned short*)(combB + off) = f2bf(acc[i][p]);
      }
  }
  __syncthreads();

  // ---- MFMA GEMM: out[pix][d] = comb[pix][k'] * pwT[d][k'], 8 waves 2Mx4N ----
  {
    const int lane = t & 63, wv = t >> 6;
    const int wm = wv & 1, wn = wv >> 1;
    const int l15 = lane & 15, l4 = lane >> 4;
    f32x4 acc[4][6];
#pragma unroll
    for (int mt = 0; mt < 4; ++mt)
#pragma unroll
      for (int nt = 0; nt < 6; ++nt) acc[mt][nt] = (f32x4){0.f,0.f,0.f,0.f};
    const char* pwTb = (const char*)P.pwT;
#pragma unroll 2
    for (int ks = 0; ks < 12; ++ks) {
      const int k0 = ks*32 + l4*8;
      s16x8 af[4], bfr[6];
#pragma unroll
      for (int mt = 0; mt < 4; ++mt) {
        const int m = wm*64 + mt*16 + l15;
        af[mt] = *(const s16x8*)(combB + m*768 + ((2*k0) ^ SWZ(m)));
      }
#pragma unroll
      for (int nt = 0; nt < 6; ++nt) {
        const int d = wn*96 + nt*16 + l15;
        bfr[nt] = *(const s16x8*)(pwTb + (size_t)d*768 + 2*k0);
      }
#pragma unroll
      for (int mt = 0; mt < 4; ++mt)
#pragma unroll
        for (int nt = 0; nt < 6; ++nt)
          acc[mt][nt] = __builtin_amdgcn_mfma_f32_16x16x32_bf16(af[mt], bfr[nt], acc[mt][nt], 0, 0, 0);
    }
#pragma unroll
    for (int nt = 0; nt < 6; ++nt) {
      const int d = wn*96 + nt*16 + l15;
      const float pbv = P.pb[d];
#pragma unroll
      for (int mt = 0; mt < 4; ++mt) {
        const int pix = wm*64 + mt*16 + l4*4;
        float4 o;
        o.x = acc[mt][nt][0] + pbv;
        o.y = acc[mt][nt][1] + pbv;
        o.z = acc[mt][nt][2] + pbv;
        o.w = acc[mt][nt][3] + pbv;
        *(float4*)&P.out[(size_t)(b*C_ + d)*HW + (h0 + (pix >> 5))*32 + (pix & 31)] = o;
      }
    }
  }
}

// ---------------------------------------------------------------------------
extern "C" void kernel_launch(void* const* d_in, const int* in_sizes, int n_in,
                              void* d_out, int out_size, void* d_ws, size_t ws_size,
                              hipStream_t stream) {
  KParams P;
  P.x = (const float*)d_in[0];
  for (int s = 0; s < 3; ++s) {
    const int base = 1 + s * 6;
    P.mw1[s] = (const float*)d_in[base + 0];
    P.mb1[s] = (const float*)d_in[base + 1];
    P.mw2[s] = (const float*)d_in[base + 2];
    P.mb2[s] = (const float*)d_in[base + 3];
    P.cw[s]  = (const float*)d_in[base + 4];
    P.cb[s]  = (const float*)d_in[base + 5];
  }
  P.fw1 = (const float*)d_in[19]; P.fb1 = (const float*)d_in[20];
  P.fw2 = (const float*)d_in[21]; P.fb2 = (const float*)d_in[22];
  P.pw  = (const float*)d_in[23]; P.pb  = (const float*)d_in[24];
  float* w = (float*)d_ws;
  P.wg     = w;                               // 36864 floats
  P.H_part = w + 36864;                       // 18432
  P.cvS    = w + 55296;                       // 245760
  P.ext    = w + 301056;                      // 122880
  P.pwT    = (unsigned short*)(w + 423936);   // 147456 ushorts (73728 f)
  P.hl     = (unsigned short*)(w + 497664);   // 2359296 ushorts (1179648 f)
  P.out = (float*)d_out;

  k_work<<<1168, 256, 0, stream>>>(P);
  k_gate<<<32, 512, 0, stream>>>(P);
  k_proj<<<256, 512, 0, stream>>>(P);
}